// Round 12
// baseline (888.796 us; speedup 1.0000x reference)
//
#include <hip/hip_runtime.h>
#include <stdint.h>

#define NN 20000      // nodes
#define NE 320000     // edges
#define NBATCH 16
#define NTILE 2500    // 128-edge tiles

typedef short short8 __attribute__((ext_vector_type(8)));   // 8 x bf16 bits (4 VGPR)
typedef float f32x4  __attribute__((ext_vector_type(4)));   // MFMA acc

__device__ __forceinline__ unsigned short f2bf(float f) {
  union { float f; unsigned u; } v; v.f = f;
  unsigned r = v.u + 0x7FFFu + ((v.u >> 16) & 1u);   // RNE
  return (unsigned short)(r >> 16);
}
__device__ __forceinline__ float bf2f(unsigned short h) {
  union { unsigned u; float f; } v; v.u = ((unsigned)h) << 16;
  return v.f;
}
__device__ __forceinline__ float bf2fs(short h) { return bf2f((unsigned short)h); }

// LDS tile: 128 edges x 256 bf16, XOR-swizzled 16B granules, exactly 64 KB.
#define HOFF(e, k) (((e) << 8) + (((((k) >> 3) ^ ((e) & 7)) << 3) + ((k) & 7)))

// ---------------- weight prep: fp32 [K,N] -> bf16 transposed [N,K] (or plain cast) ----------------
struct TD { const float* s; unsigned short* d; int R, C, r0, ld; };
struct TDs { TD t[13]; };

__global__ void wprep(TDs all) {
  TD td = all.t[blockIdx.y];
  int stride = gridDim.x * blockDim.x;
  int i0 = blockIdx.x * blockDim.x + threadIdx.x;
  if (td.ld == 0) {                       // plain cast copy
    for (int i = i0; i < td.R; i += stride) td.d[i] = f2bf(td.s[i]);
  } else {                                // dst[c*R + r] = src[(r0+r)*ld + c]
    int total = td.R * td.C;
    for (int i = i0; i < total; i += stride) {
      int c = i / td.R;
      int r = i - c * td.R;
      td.d[i] = f2bf(td.s[(size_t)(td.r0 + r) * td.ld + c]);
    }
  }
}

// ---------------- CSR build (dst-sorted edge permutation) ----------------
__global__ void hist_kernel(const int* __restrict__ dstI, int* __restrict__ deg) {
  int e = blockIdx.x * 256 + threadIdx.x;
  if (e < NE) atomicAdd(&deg[dstI[e]], 1);
}

// block 0: exclusive scan of deg; blocks 1..79: batch bounds; block 80: bias concat vectors
__global__ void scan_bounds(const int* __restrict__ deg, int* __restrict__ rowstart,
                            int* __restrict__ cursor, const int* __restrict__ batch,
                            int* __restrict__ bstart,
                            const float* __restrict__ g1b1, const float* __restrict__ g2b1,
                            float* __restrict__ b1cat1, float* __restrict__ b1cat2) {
  if (blockIdx.x == 0) {
    __shared__ int part[256];
    int t = threadIdx.x;
    int c0 = t * 80; if (c0 > NN) c0 = NN;
    int c1 = c0 + 80; if (c1 > NN) c1 = NN;
    int s = 0;
    for (int i = c0; i < c1; ++i) s += deg[i];
    part[t] = s;
    __syncthreads();
    if (t == 0) {
      int run = 0;
      for (int i = 0; i < 256; ++i) { int v = part[i]; part[i] = run; run += v; }
    }
    __syncthreads();
    int run = part[t];
    for (int i = c0; i < c1; ++i) { rowstart[i] = run; cursor[i] = run; run += deg[i]; }
    if (t == 255) rowstart[NN] = run;   // == NE
  } else if (blockIdx.x == 80) {
    int t = threadIdx.x;
    b1cat1[t] = g1b1[t]; b1cat1[256 + t] = 0.f;
    b1cat2[t] = g2b1[t]; b1cat2[256 + t] = 0.f;
  } else {
    int n = (blockIdx.x - 1) * 256 + threadIdx.x;
    if (n >= NN) return;
    int bn = batch[n];
    if (n == 0) {
      for (int b2 = 0; b2 <= bn; ++b2) bstart[b2] = 0;
    } else {
      int bp = batch[n - 1];
      for (int b2 = bp + 1; b2 <= bn; ++b2) bstart[b2] = n;
    }
    if (n == NN - 1) {
      for (int b2 = bn + 1; b2 <= NBATCH; ++b2) bstart[b2] = NN;
    }
  }
}

__global__ void fillcsr(const int* __restrict__ srcI, const int* __restrict__ dstI,
                        int* __restrict__ cursor, int* __restrict__ sSrc,
                        int* __restrict__ sDst) {
  int e = blockIdx.x * 256 + threadIdx.x;
  if (e < NE) {
    int d = dstI[e];
    int slot = atomicAdd(&cursor[d], 1);
    sDst[slot] = d;
    sSrc[slot] = srcI[e];
  }
}

// ---------------- generic transposed-weight GEMM: Out[r][f] = In[r][:] . WT[f][:] + bias ----------------
__global__ __launch_bounds__(512, 4) void gemmT(
    const unsigned short* __restrict__ WT, const unsigned short* __restrict__ In,
    const float* __restrict__ bias, unsigned short* __restrict__ Out,
    int M, int K, int Nout, int ldo) {
  const int tid = threadIdx.x;
  const int lane = tid & 63, w = tid >> 6;
  const int wf = w >> 1, we = w & 1;
  const int l15 = lane & 15, q = lane >> 4;
  const int fb = blockIdx.x * 256 + wf * 64;
  const int rb = blockIdx.y * 128 + we * 64;
  f32x4 acc[4][4] = {};
  const short8 zz = {0, 0, 0, 0, 0, 0, 0, 0};
  for (int kc = 0; kc < K; kc += 32) {
    short8 a[4], bq[4];
#pragma unroll
    for (int i = 0; i < 4; ++i) {
      if (fb + i * 16 < Nout)
        a[i] = *(const short8*)(WT + (size_t)(fb + i * 16 + l15) * K + kc + q * 8);
      else
        a[i] = zz;
      int r = rb + i * 16 + l15;
      if (r >= M) r = M - 1;  // clamp: stores guarded below
      bq[i] = *(const short8*)(In + (size_t)r * K + kc + q * 8);
    }
#pragma unroll
    for (int i = 0; i < 4; ++i)
#pragma unroll
      for (int j = 0; j < 4; ++j)
        acc[i][j] = __builtin_amdgcn_mfma_f32_16x16x32_bf16(a[i], bq[j], acc[i][j], 0, 0, 0);
  }
#pragma unroll
  for (int i = 0; i < 4; ++i) {
    int f0 = fb + i * 16 + q * 4;
    if (f0 >= Nout) continue;
    float4 bs = make_float4(0.f, 0.f, 0.f, 0.f);
    if (bias) bs = *(const float4*)(bias + f0);
#pragma unroll
    for (int j = 0; j < 4; ++j) {
      int r = rb + j * 16 + l15;
      if (r >= M) continue;
      ushort4 o;
      o.x = f2bf(acc[i][j][0] + bs.x);
      o.y = f2bf(acc[i][j][1] + bs.y);
      o.z = f2bf(acc[i][j][2] + bs.z);
      o.w = f2bf(acc[i][j][3] + bs.w);
      *(ushort4*)(Out + (size_t)r * ldo + f0) = o;
    }
  }
}

// ---------------- fused per-edge MLP + dst-segmented aggregation ----------------
// phase 0 widened to 8 outstanding loads/thread (32-VGPR staging window; peak ~105 regs
// of the 128 unified budget -> no spill). Segment-flag pass moved into phase 0 so its
// atomic latency hides under the GEMM phases.
// h1 = relu(PQ[sDst][0:256] + PQ[sSrc][256:512])  (b1 pre-folded into PQ dst half)
// h2 = relu(h1 @ W2 + b2); m = h2 @ W3 (bf16 LDS); segmented dst-run sum -> agg (+len*b3)
__global__ __launch_bounds__(512, 4) void edge_mlp_f(
    const unsigned short* __restrict__ PQ, const int* __restrict__ sSrc,
    const int* __restrict__ sDst,
    const unsigned short* __restrict__ W2T, const float* __restrict__ b2,
    const unsigned short* __restrict__ W3T, const float* __restrict__ b3,
    int* __restrict__ segcnt, int* __restrict__ segbuf, float* __restrict__ agg) {
  __shared__ __align__(16) unsigned short h[128 * 256];  // 64 KB -> 2 blocks/CU
  const int tid = threadIdx.x;
  const int e0 = blockIdx.x * 128;

  {  // phase 0: gather + h1, 2 chunks x 8 outstanding loads
    int r = tid & 127;
    int c0 = (tid >> 7) * 64;
    int dn = sDst[e0 + r];
    int sn = sSrc[e0 + r];
    const unsigned short* pd = PQ + (size_t)dn * 512 + c0;
    const unsigned short* ps = PQ + (size_t)sn * 512 + 256 + c0;
#pragma unroll
    for (int ch = 0; ch < 2; ++ch) {
      short8 dv[4], sv[4];
#pragma unroll
      for (int i = 0; i < 4; ++i) {
        dv[i] = *(const short8*)(pd + (ch * 4 + i) * 8);
        sv[i] = *(const short8*)(ps + (ch * 4 + i) * 8);
      }
#pragma unroll
      for (int i = 0; i < 4; ++i) {
        short8 o;
#pragma unroll
        for (int j = 0; j < 8; ++j) {
          float v = bf2fs(dv[i][j]) + bf2fs(sv[i][j]);
          o[j] = (short)f2bf(fmaxf(v, 0.f));
        }
        *(short8*)&h[HOFF(r, c0 + (ch * 4 + i) * 8)] = o;
      }
    }
    if (tid < 128) {  // segment flags (latency hides under GEMM phases)
      int d0 = sDst[e0 + tid];
      bool flag = (tid == 0) || (sDst[e0 + tid - 1] != d0);
      if (flag) {
        int idx = atomicAdd(&segcnt[blockIdx.x], 1);
        segbuf[blockIdx.x * 128 + idx] = tid;
      }
    }
  }
  __syncthreads();

  const int lane = tid & 63, w = tid >> 6;
  const int wf = w >> 1, we = w & 1;
  const int l15 = lane & 15, q = lane >> 4;
  const int fb = wf * 64, eb = we * 64;
  f32x4 acc[4][4];

  // ---- GEMM1: h2^T = W2T @ h1^T ----
#pragma unroll
  for (int i = 0; i < 4; ++i)
#pragma unroll
    for (int j = 0; j < 4; ++j) { f32x4 z = {0.f, 0.f, 0.f, 0.f}; acc[i][j] = z; }
  for (int kc = 0; kc < 256; kc += 32) {
    short8 a[4], bq[4];
#pragma unroll
    for (int i = 0; i < 4; ++i)
      a[i] = *(const short8*)(W2T + (size_t)(fb + i * 16 + l15) * 256 + kc + q * 8);
#pragma unroll
    for (int j = 0; j < 4; ++j)
      bq[j] = *(const short8*)&h[HOFF(eb + j * 16 + l15, kc + q * 8)];
#pragma unroll
    for (int i = 0; i < 4; ++i)
#pragma unroll
      for (int j = 0; j < 4; ++j)
        acc[i][j] = __builtin_amdgcn_mfma_f32_16x16x32_bf16(a[i], bq[j], acc[i][j], 0, 0, 0);
  }
  __syncthreads();  // all reads of h1 done
#pragma unroll
  for (int i = 0; i < 4; ++i) {
    int f0 = fb + i * 16 + q * 4;
    float4 bs = *(const float4*)(b2 + f0);
#pragma unroll
    for (int j = 0; j < 4; ++j) {
      int e = eb + j * 16 + l15;
      ushort4 o;
      o.x = f2bf(fmaxf(acc[i][j][0] + bs.x, 0.f));
      o.y = f2bf(fmaxf(acc[i][j][1] + bs.y, 0.f));
      o.z = f2bf(fmaxf(acc[i][j][2] + bs.z, 0.f));
      o.w = f2bf(fmaxf(acc[i][j][3] + bs.w, 0.f));
      *(ushort4*)&h[HOFF(e, f0)] = o;  // h2
    }
  }
  __syncthreads();

  // ---- GEMM2: m^T = W3T @ h2^T ----
#pragma unroll
  for (int i = 0; i < 4; ++i)
#pragma unroll
    for (int j = 0; j < 4; ++j) { f32x4 z = {0.f, 0.f, 0.f, 0.f}; acc[i][j] = z; }
  for (int kc = 0; kc < 256; kc += 32) {
    short8 a[4], bq[4];
#pragma unroll
    for (int i = 0; i < 4; ++i)
      a[i] = *(const short8*)(W3T + (size_t)(fb + i * 16 + l15) * 256 + kc + q * 8);
#pragma unroll
    for (int j = 0; j < 4; ++j)
      bq[j] = *(const short8*)&h[HOFF(eb + j * 16 + l15, kc + q * 8)];
#pragma unroll
    for (int i = 0; i < 4; ++i)
#pragma unroll
      for (int j = 0; j < 4; ++j)
        acc[i][j] = __builtin_amdgcn_mfma_f32_16x16x32_bf16(a[i], bq[j], acc[i][j], 0, 0, 0);
  }
  __syncthreads();  // all reads of h2 done before overwrite
#pragma unroll
  for (int i = 0; i < 4; ++i) {
    int f0 = fb + i * 16 + q * 4;
#pragma unroll
    for (int j = 0; j < 4; ++j) {
      int e = eb + j * 16 + l15;
      ushort4 o;
      o.x = f2bf(acc[i][j][0]); o.y = f2bf(acc[i][j][1]);
      o.z = f2bf(acc[i][j][2]); o.w = f2bf(acc[i][j][3]);
      *(ushort4*)&h[HOFF(e, f0)] = o;  // m
    }
  }
  __syncthreads();

  // segmented reduction: 8 groups x 64 lanes (4 feats/lane), fp32
  {
    int cnt = segcnt[blockIdx.x];
    int f4 = (tid & 63) * 4;
    int sg = tid >> 6;
    const int* sb = segbuf + blockIdx.x * 128;
    float4 b3v = *(const float4*)(b3 + f4);
    for (int k = sg; k < cnt; k += 8) {
      int start = sb[k];
      int end = 128;
      for (int j2 = 0; j2 < cnt; ++j2) {
        int v = sb[j2];
        if (v > start && v < end) end = v;
      }
      int node = sDst[e0 + start];
      float s0 = 0.f, s1 = 0.f, s2 = 0.f, s3 = 0.f;
      for (int rr = start; rr < end; ++rr) {
        ushort4 v = *(const ushort4*)&h[HOFF(rr, f4)];
        s0 += bf2f(v.x); s1 += bf2f(v.y); s2 += bf2f(v.z); s3 += bf2f(v.w);
      }
      float c = (float)(end - start);
      s0 += c * b3v.x; s1 += c * b3v.y; s2 += c * b3v.z; s3 += c * b3v.w;
      float* pr = agg + (size_t)node * 256 + f4;
      if (start == 0 || end == 128) {  // run may continue in neighbor tile
        atomicAdd(pr + 0, s0); atomicAdd(pr + 1, s1);
        atomicAdd(pr + 2, s2); atomicAdd(pr + 3, s3);
      } else {                         // wholly inside this tile: unique owner
        *(float4*)pr = make_float4(s0, s1, s2, s3);
      }
    }
  }
}

// ---------------- relu + layernorm, fp32 in -> bf16 out ----------------
__global__ void relu_ln(const float* __restrict__ agg, const float* __restrict__ g,
                        const float* __restrict__ b, unsigned short* __restrict__ out) {
  int row = blockIdx.x * 4 + (threadIdx.x >> 6);
  int lane = threadIdx.x & 63;
  if (row >= NN) return;
  float4 v = *(const float4*)(agg + (size_t)row * 256 + lane * 4);
  v.x = fmaxf(v.x, 0.f); v.y = fmaxf(v.y, 0.f); v.z = fmaxf(v.z, 0.f); v.w = fmaxf(v.w, 0.f);
  float s = v.x + v.y + v.z + v.w;
  float sq = v.x * v.x + v.y * v.y + v.z * v.z + v.w * v.w;
  for (int off = 32; off >= 1; off >>= 1) {
    s += __shfl_xor(s, off);
    sq += __shfl_xor(sq, off);
  }
  float mu = s * (1.f / 256.f);
  float var = sq * (1.f / 256.f) - mu * mu;
  float rs = rsqrtf(var + 1e-5f);
  float4 gg = *(const float4*)(g + lane * 4);
  float4 bb = *(const float4*)(b + lane * 4);
  ushort4 o;
  o.x = f2bf((v.x - mu) * rs * gg.x + bb.x);
  o.y = f2bf((v.y - mu) * rs * gg.y + bb.y);
  o.z = f2bf((v.z - mu) * rs * gg.z + bb.z);
  o.w = f2bf((v.w - mu) * rs * gg.w + bb.w);
  *(ushort4*)(out + (size_t)row * 256 + lane * 4) = o;
}

// ---------------- fused assignment MLP + gumbel softmax (64 node-rows per block) ----------------
__global__ __launch_bounds__(512, 4) void assign_gumbel(
    const unsigned short* __restrict__ x2b, const unsigned short* __restrict__ aw1T,
    const float* __restrict__ ab1, const unsigned short* __restrict__ aw2T,
    const float* __restrict__ ab2, const float* __restrict__ u,
    float* __restrict__ sf, float* __restrict__ entacc, float* __restrict__ avgacc) {
  __shared__ __align__(16) unsigned short sh[64 * 256];   // 32 KB
  __shared__ float sh_logit[64 * 33];
  __shared__ float lavg[32];
  __shared__ float lent;
  const int tid = threadIdx.x;
  const int n0 = blockIdx.x * 64;
  if (tid < 32) lavg[tid] = 0.f;
  if (tid == 0) lent = 0.f;

  const int lane = tid & 63, w = tid >> 6;
  const int l15 = lane & 15, q = lane >> 4;

  {  // phase A: assh tile
    const int wf = w >> 1, we = w & 1;
    const int fb = wf * 64, eb = we * 32;
    f32x4 acc[4][2];
#pragma unroll
    for (int i = 0; i < 4; ++i)
#pragma unroll
      for (int j = 0; j < 2; ++j) { f32x4 z = {0.f, 0.f, 0.f, 0.f}; acc[i][j] = z; }
    for (int kc = 0; kc < 256; kc += 32) {
      short8 a[4], bq[2];
#pragma unroll
      for (int i = 0; i < 4; ++i)
        a[i] = *(const short8*)(aw1T + (size_t)(fb + i * 16 + l15) * 256 + kc + q * 8);
#pragma unroll
      for (int j = 0; j < 2; ++j) {
        int rr = n0 + eb + j * 16 + l15;
        if (rr >= NN) rr = NN - 1;
        bq[j] = *(const short8*)(x2b + (size_t)rr * 256 + kc + q * 8);
      }
#pragma unroll
      for (int i = 0; i < 4; ++i)
#pragma unroll
        for (int j = 0; j < 2; ++j)
          acc[i][j] = __builtin_amdgcn_mfma_f32_16x16x32_bf16(a[i], bq[j], acc[i][j], 0, 0, 0);
    }
#pragma unroll
    for (int i = 0; i < 4; ++i) {
      int f0 = fb + i * 16 + q * 4;
      float4 bs = *(const float4*)(ab1 + f0);
#pragma unroll
      for (int j = 0; j < 2; ++j) {
        int e = eb + j * 16 + l15;
        ushort4 o;
        o.x = f2bf(fmaxf(acc[i][j][0] + bs.x, 0.f));
        o.y = f2bf(fmaxf(acc[i][j][1] + bs.y, 0.f));
        o.z = f2bf(fmaxf(acc[i][j][2] + bs.z, 0.f));
        o.w = f2bf(fmaxf(acc[i][j][3] + bs.w, 0.f));
        *(ushort4*)&sh[HOFF(e, f0)] = o;
      }
    }
  }
  __syncthreads();

  {  // phase B: logits (N=32). wave w: row-group rg=w&3, feat-group fg=w>>2 (fg<2)
    const int rg = w & 3, fg = w >> 2;
    if (fg < 2) {
      f32x4 acc = {0.f, 0.f, 0.f, 0.f};
      for (int kc = 0; kc < 256; kc += 32) {
        short8 a = *(const short8*)(aw2T + (size_t)(fg * 16 + l15) * 256 + kc + q * 8);
        short8 bq = *(const short8*)&sh[HOFF(rg * 16 + l15, kc + q * 8)];
        acc = __builtin_amdgcn_mfma_f32_16x16x32_bf16(a, bq, acc, 0, 0, 0);
      }
      int rowL = rg * 16 + l15;
#pragma unroll
      for (int t2 = 0; t2 < 4; ++t2) {
        int f = fg * 16 + q * 4 + t2;
        sh_logit[rowL * 33 + f] = acc[t2] + ab2[f];
      }
    }
  }
  __syncthreads();

  // phase C: gumbel softmax, 4 threads per row (8 slots each)
  if (tid < 256) {
    int rowL = tid >> 2, sub = tid & 3;
    int n = n0 + rowL;
    if (n < NN) {
      int j0 = sub * 8;
      float z[8];
      float4 u0 = *(const float4*)(u + (size_t)n * 32 + j0);
      float4 u1 = *(const float4*)(u + (size_t)n * 32 + j0 + 4);
      float uu[8] = {u0.x, u0.y, u0.z, u0.w, u1.x, u1.y, u1.z, u1.w};
      float m = -1e30f;
#pragma unroll
      for (int j = 0; j < 8; ++j) {
        z[j] = sh_logit[rowL * 33 + j0 + j] - logf(-logf(uu[j] + 1e-9f) + 1e-9f);
        m = fmaxf(m, z[j]);
      }
      m = fmaxf(m, __shfl_xor(m, 1));
      m = fmaxf(m, __shfl_xor(m, 2));
      float sum = 0.f;
#pragma unroll
      for (int j = 0; j < 8; ++j) { z[j] = expf(z[j] - m); sum += z[j]; }
      sum += __shfl_xor(sum, 1);
      sum += __shfl_xor(sum, 2);
      float inv = 1.f / sum;
      float ent = 0.f;
      float so[8];
#pragma unroll
      for (int j = 0; j < 8; ++j) {
        float sj = z[j] * inv;
        so[j] = sj;
        ent += sj * logf(sj + 1e-9f);
        atomicAdd(&lavg[j0 + j], sj);
      }
      *(float4*)(sf + (size_t)n * 32 + j0) = make_float4(so[0], so[1], so[2], so[3]);
      *(float4*)(sf + (size_t)n * 32 + j0 + 4) = make_float4(so[4], so[5], so[6], so[7]);
      ent += __shfl_xor(ent, 1);
      ent += __shfl_xor(ent, 2);
      if (sub == 0) atomicAdd(&lent, ent);
    }
  }
  __syncthreads();
  if (tid < 32) atomicAdd(&avgacc[tid], lavg[tid]);
  if (tid == 0) atomicAdd(entacc, lent);
}

// ---------------- pooled[b,s,h] = sum_n x2[n,h]*s[n,s] ----------------
__global__ void pool_kernel(const unsigned short* __restrict__ x2b, const float* __restrict__ sf,
                            const int* __restrict__ bstart, float* __restrict__ pooled) {
  int b = blockIdx.x, ci = blockIdx.y;
  int n0b = bstart[b], n1b = bstart[b + 1];
  int t = threadIdx.x;
  int si = t >> 3;          // 0..31
  int hb = (t & 7) * 32;    // 0..224
  float acc[32];
#pragma unroll
  for (int k = 0; k < 32; ++k) acc[k] = 0.f;
  for (int nst = n0b + ci * 128; nst < n1b; nst += gridDim.y * 128) {
    int nend = (nst + 128 < n1b) ? nst + 128 : n1b;
    for (int n = nst; n < nend; ++n) {
      float sv = sf[(size_t)n * 32 + si];
      const unsigned short* xr = x2b + (size_t)n * 256 + hb;
#pragma unroll
      for (int k2 = 0; k2 < 4; ++k2) {
        short8 xv = *(const short8*)(xr + k2 * 8);
#pragma unroll
        for (int jj = 0; jj < 8; ++jj) acc[k2 * 8 + jj] = fmaf(sv, bf2fs(xv[jj]), acc[k2 * 8 + jj]);
      }
    }
  }
  float* pp = pooled + (size_t)(b * 32 + si) * 256 + hb;
#pragma unroll
  for (int k = 0; k < 32; ++k) atomicAdd(pp + k, acc[k]);
}

// ---------------- fused output MLP (+ loss in block 0): latent = relu(pooled@ow1+ob1)@ow2+ob2 ----
__global__ __launch_bounds__(512, 4) void out_mlp(
    const float* __restrict__ pooled, const unsigned short* __restrict__ ow1T,
    const float* __restrict__ ob1, const unsigned short* __restrict__ ow2T,
    const float* __restrict__ ob2, float* __restrict__ latent,
    const float* __restrict__ accs, float* __restrict__ outloss) {
  __shared__ __align__(16) unsigned short sh[64 * 256];   // hid tile, 32 KB
  const int tid = threadIdx.x;
  const int n0 = blockIdx.x * 64;
  const int lane = tid & 63, w = tid >> 6;
  const int l15 = lane & 15, q = lane >> 4;

  if (blockIdx.x == 0 && tid < 64) {  // loss (accs ready: assign_gumbel completed earlier)
    float d = 0.f;
    if (tid < 32) {
      float a = accs[16 + tid] * (1.f / NN);
      d = a * logf(a + 1e-9f);
    }
    for (int off = 32; off >= 1; off >>= 1) d += __shfl_xor(d, off);
    if (tid == 0) outloss[0] = -accs[0] * (1.f / NN) + d;
  }

  {  // phase A: hid = relu(pooled @ ow1 + ob1), pooled converted inline to bf16
    const int wf = w >> 1, we = w & 1;
    const int fb = wf * 64, eb = we * 32;
    f32x4 acc[4][2];
#pragma unroll
    for (int i = 0; i < 4; ++i)
#pragma unroll
      for (int j = 0; j < 2; ++j) { f32x4 z = {0.f, 0.f, 0.f, 0.f}; acc[i][j] = z; }
    for (int kc = 0; kc < 256; kc += 32) {
      short8 a[4], bq[2];
#pragma unroll
      for (int i = 0; i < 4; ++i)
        a[i] = *(const short8*)(ow1T + (size_t)(fb + i * 16 + l15) * 256 + kc + q * 8);
#pragma unroll
      for (int j = 0; j < 2; ++j) {
        int rr = n0 + eb + j * 16 + l15;
        const float* pr = pooled + (size_t)rr * 256 + kc + q * 8;
        float4 lo = *(const float4*)pr;
        float4 hi = *(const float4*)(pr + 4);
        short8 o;
        o[0] = (short)f2bf(lo.x); o[1] = (short)f2bf(lo.y);
        o[2] = (short)f2bf(lo.z); o[3] = (short)f2bf(lo.w);
        o[4] = (short)f2bf(hi.x); o[5] = (short)f2bf(hi.y);
        o[6] = (short)f2bf(hi.z); o[7] = (short)f2bf(hi.w);
        bq[j] = o;
      }
#pragma unroll
      for (int i = 0; i < 4; ++i)
#pragma unroll
        for (int j = 0; j < 2; ++j)
          acc[i][j] = __builtin_amdgcn_mfma_f32_16x16x32_bf16(a[i], bq[j], acc[i][j], 0, 0, 0);
    }
#pragma unroll
    for (int i = 0; i < 4; ++i) {
      int f0 = fb + i * 16 + q * 4;
      float4 bs = *(const float4*)(ob1 + f0);
#pragma unroll
      for (int j = 0; j < 2; ++j) {
        int e = eb + j * 16 + l15;
        ushort4 o;
        o.x = f2bf(fmaxf(acc[i][j][0] + bs.x, 0.f));
        o.y = f2bf(fmaxf(acc[i][j][1] + bs.y, 0.f));
        o.z = f2bf(fmaxf(acc[i][j][2] + bs.z, 0.f));
        o.w = f2bf(fmaxf(acc[i][j][3] + bs.w, 0.f));
        *(ushort4*)&sh[HOFF(e, f0)] = o;
      }
    }
  }
  __syncthreads();

  {  // phase B: latent = hid @ ow2 + ob2 (Nout=128)
    const int wf = w >> 1, we = w & 1;
    const int fb = wf * 32, eb = we * 32;
    f32x4 acc[2][2];
#pragma unroll
    for (int i = 0; i < 2; ++i)
#pragma unroll
      for (int j = 0; j < 2; ++j) { f32x4 z = {0.f, 0.f, 0.f, 0.f}; acc[i][j] = z; }
    for (int kc = 0; kc < 256; kc += 32) {
      short8 a[2], bq[2];
#pragma unroll
      for (int i = 0; i < 2; ++i)
        a[i] = *(const short8*)(ow2T + (size_t)(fb + i * 16 + l15) * 256 + kc + q * 8);
#pragma unroll
      for (int j = 0; j < 2; ++j)
        bq[j] = *(const short8*)&sh[HOFF(eb + j * 16 + l15, kc + q * 8)];
#pragma unroll
      for (int i = 0; i < 2; ++i)
#pragma unroll
        for (int j = 0; j < 2; ++j)
          acc[i][j] = __builtin_amdgcn_mfma_f32_16x16x32_bf16(a[i], bq[j], acc[i][j], 0, 0, 0);
    }
#pragma unroll
    for (int i = 0; i < 2; ++i) {
      int f0 = fb + i * 16 + q * 4;
      float4 bs = *(const float4*)(ob2 + f0);
#pragma unroll
      for (int j = 0; j < 2; ++j) {
        int rr = n0 + eb + j * 16 + l15;
        *(float4*)(latent + (size_t)rr * 128 + f0) =
            make_float4(acc[i][j][0] + bs.x, acc[i][j][1] + bs.y,
                        acc[i][j][2] + bs.z, acc[i][j][3] + bs.w);
      }
    }
  }
}

// ---------------- orchestration ----------------
extern "C" void kernel_launch(void* const* d_in, const int* in_sizes, int n_in,
                              void* d_out, int out_size, void* d_ws, size_t ws_size,
                              hipStream_t stream) {
  (void)in_sizes; (void)n_in; (void)out_size; (void)ws_size;
  const float* x = (const float*)d_in[0];
  const float* u = (const float*)d_in[1];
  const int* ei = (const int*)d_in[2];
  const int* batch = (const int*)d_in[3];
  const float* g1w1 = (const float*)d_in[4];
  const float* g1b1 = (const float*)d_in[5];
  const float* g1w2 = (const float*)d_in[6];
  const float* g1b2 = (const float*)d_in[7];
  const float* g1w3 = (const float*)d_in[8];
  const float* g1b3 = (const float*)d_in[9];
  const float* ln1g = (const float*)d_in[10];
  const float* ln1b = (const float*)d_in[11];
  const float* g2w1 = (const float*)d_in[12];
  const float* g2b1 = (const float*)d_in[13];
  const float* g2w2 = (const float*)d_in[14];
  const float* g2b2 = (const float*)d_in[15];
  const float* g2w3 = (const float*)d_in[16];
  const float* g2b3 = (const float*)d_in[17];
  const float* ln2g = (const float*)d_in[18];
  const float* ln2b = (const float*)d_in[19];
  const float* aw1 = (const float*)d_in[20];
  const float* ab1 = (const float*)d_in[21];
  const float* aw2 = (const float*)d_in[22];
  const float* ab2 = (const float*)d_in[23];
  const float* ow1 = (const float*)d_in[24];
  const float* ob1 = (const float*)d_in[25];
  const float* ow2 = (const float*)d_in[26];
  const float* ob2 = (const float*)d_in[27];
  const int* srcI = ei;        // edge_index[0] = src
  const int* dstI = ei + NE;   // edge_index[1] = dst

  char* wp = (char*)d_ws;
  size_t off = 0;
  auto alloc = [&](size_t bytes) {
    void* p = wp + off;
    off += (bytes + 255) & ~(size_t)255;
    return p;
  };
  unsigned short* W1catT = (unsigned short*)alloc((size_t)512 * 64 * 2);
  unsigned short* W2catT = (unsigned short*)alloc((size_t)512 * 256 * 2);
  unsigned short* g1w2T = (unsigned short*)alloc((size_t)256 * 256 * 2);
  unsigned short* g1w3T = (unsigned short*)alloc((size_t)256 * 256 * 2);
  unsigned short* g2w2T = (unsigned short*)alloc((size_t)256 * 256 * 2);
  unsigned short* g2w3T = (unsigned short*)alloc((size_t)256 * 256 * 2);
  unsigned short* aw1T = (unsigned short*)alloc((size_t)256 * 256 * 2);
  unsigned short* aw2T = (unsigned short*)alloc((size_t)32 * 256 * 2);
  unsigned short* ow1T = (unsigned short*)alloc((size_t)256 * 256 * 2);
  unsigned short* ow2T = (unsigned short*)alloc((size_t)128 * 256 * 2);
  unsigned short* xb = (unsigned short*)alloc((size_t)NN * 64 * 2);
  unsigned short* PQ = (unsigned short*)alloc((size_t)NN * 512 * 2);
  unsigned short* x1b = (unsigned short*)alloc((size_t)NN * 256 * 2);
  unsigned short* x2b = (unsigned short*)alloc((size_t)NN * 256 * 2);
  int* bstart = (int*)alloc(32 * 4);
  int* cursor = (int*)alloc((size_t)NN * 4);
  int* rowstart = (int*)alloc((size_t)(NN + 1) * 4);
  int* sSrc = (int*)alloc((size_t)NE * 4);
  int* sDst = (int*)alloc((size_t)NE * 4);
  int* segbuf = (int*)alloc((size_t)2 * NTILE * 128 * 4);
  float* b1cat1 = (float*)alloc(512 * 4);
  float* b1cat2 = (float*)alloc(512 * 4);
  // ---- contiguous zero-init region (single memset) ----
  char* zbase = (char*)(wp + off);
  float* accs = (float*)alloc(64 * 4);
  float* pooled = (float*)alloc((size_t)512 * 256 * 4);
  int* deg = (int*)alloc((size_t)NN * 4);
  int* segcnt = (int*)alloc((size_t)2 * NTILE * 4);
  float* agg1 = (float*)alloc((size_t)NN * 256 * 4);
  float* agg2 = (float*)alloc((size_t)NN * 256 * 4);
  size_t zbytes = (size_t)((char*)(wp + off) - zbase);

  float* out_f = (float*)d_out;
  float* out_latent = out_f;                 // [16*32*128] = 65536
  float* out_s = out_f + 65536;              // [20000*32]
  float* out_loss = out_f + 65536 + 640000;  // [1]

  TDs tds;
  tds.t[0] = {g1w1, W1catT, 64, 256, 0, 256};
  tds.t[1] = {g1w1, W1catT + 256 * 64, 64, 256, 64, 256};
  tds.t[2] = {g1w2, g1w2T, 256, 256, 0, 256};
  tds.t[3] = {g1w3, g1w3T, 256, 256, 0, 256};
  tds.t[4] = {g2w1, W2catT, 256, 256, 0, 256};
  tds.t[5] = {g2w1, W2catT + 256 * 256, 256, 256, 256, 256};
  tds.t[6] = {g2w2, g2w2T, 256, 256, 0, 256};
  tds.t[7] = {g2w3, g2w3T, 256, 256, 0, 256};
  tds.t[8] = {aw1, aw1T, 256, 256, 0, 256};
  tds.t[9] = {aw2, aw2T, 256, 32, 0, 32};
  tds.t[10] = {ow1, ow1T, 256, 256, 0, 256};
  tds.t[11] = {ow2, ow2T, 256, 128, 0, 128};
  tds.t[12] = {x, xb, NN * 64, 1, 0, 0};

  (void)hipMemsetAsync(zbase, 0, zbytes, stream);   // accs+pooled+deg+segcnt+agg1+agg2
  wprep<<<dim3(128, 13), 256, 0, stream>>>(tds);

  // CSR build + batch bounds + bias concat
  hist_kernel<<<dim3(1250), 256, 0, stream>>>(dstI, deg);
  scan_bounds<<<dim3(81), 256, 0, stream>>>(deg, rowstart, cursor, batch, bstart,
                                            g1b1, g2b1, b1cat1, b1cat2);
  fillcsr<<<dim3(1250), 256, 0, stream>>>(srcI, dstI, cursor, sSrc, sDst);

  // layer 1 (b1 folded into PQ dst half)
  gemmT<<<dim3(2, 157), 512, 0, stream>>>(W1catT, xb, b1cat1, PQ, NN, 64, 512, 512);
  edge_mlp_f<<<dim3(NTILE), 512, 0, stream>>>(PQ, sSrc, sDst, g1w2T, g1b2, g1w3T, g1b3,
                                              segcnt, segbuf, agg1);
  relu_ln<<<dim3(5000), 256, 0, stream>>>(agg1, ln1g, ln1b, x1b);

  // layer 2
  gemmT<<<dim3(2, 157), 512, 0, stream>>>(W2catT, x1b, b1cat2, PQ, NN, 256, 512, 512);
  edge_mlp_f<<<dim3(NTILE), 512, 0, stream>>>(PQ, sSrc, sDst, g2w2T, g2b2, g2w3T, g2b3,
                                              segcnt + NTILE, segbuf + (size_t)NTILE * 128, agg2);
  relu_ln<<<dim3(5000), 256, 0, stream>>>(agg2, ln2g, ln2b, x2b);

  // fused assignment MLP + gumbel softmax (s fp32 to d_out)
  assign_gumbel<<<dim3(313), 512, 0, stream>>>(x2b, aw1T, ab1, aw2T, ab2, u,
                                               out_s, accs, accs + 16);

  // pooling + fused output MLP (+loss)
  pool_kernel<<<dim3(16, 12), 256, 0, stream>>>(x2b, out_s, bstart, pooled);
  out_mlp<<<dim3(8), 512, 0, stream>>>(pooled, ow1T, ob1, ow2T, ob2, out_latent,
                                       accs, out_loss);
}

// Round 13
// 872.959 us; speedup vs baseline: 1.0181x; 1.0181x over previous
//
#include <hip/hip_runtime.h>
#include <stdint.h>

#define NN 20000      // nodes
#define NE 320000     // edges
#define NBATCH 16
#define NTILE 2500    // 128-edge tiles

typedef short short8 __attribute__((ext_vector_type(8)));   // 8 x bf16 bits (4 VGPR)
typedef float f32x4  __attribute__((ext_vector_type(4)));   // MFMA acc

__device__ __forceinline__ unsigned short f2bf(float f) {
  union { float f; unsigned u; } v; v.f = f;
  unsigned r = v.u + 0x7FFFu + ((v.u >> 16) & 1u);   // RNE
  return (unsigned short)(r >> 16);
}
__device__ __forceinline__ float bf2f(unsigned short h) {
  union { unsigned u; float f; } v; v.u = ((unsigned)h) << 16;
  return v.f;
}
__device__ __forceinline__ float bf2fs(short h) { return bf2f((unsigned short)h); }

// LDS tile: 128 edges x 256 bf16, XOR-swizzled 16B granules, exactly 64 KB.
#define HOFF(e, k) (((e) << 8) + (((((k) >> 3) ^ ((e) & 7)) << 3) + ((k) & 7)))

// ---------------- weight prep (+ degree histogram in blockIdx.y==13) ----------------
struct TD { const float* s; unsigned short* d; int R, C, r0, ld; };
struct TDs { TD t[13]; };

__global__ void wprep(TDs all, const int* __restrict__ dstI, int* __restrict__ deg) {
  if (blockIdx.y == 13) {   // degree histogram (independent of weight prep)
    int stride = gridDim.x * blockDim.x;
    for (int e = blockIdx.x * blockDim.x + threadIdx.x; e < NE; e += stride)
      atomicAdd(&deg[dstI[e]], 1);
    return;
  }
  TD td = all.t[blockIdx.y];
  int stride = gridDim.x * blockDim.x;
  int i0 = blockIdx.x * blockDim.x + threadIdx.x;
  if (td.ld == 0) {                       // plain cast copy
    for (int i = i0; i < td.R; i += stride) td.d[i] = f2bf(td.s[i]);
  } else {                                // dst[c*R + r] = src[(r0+r)*ld + c]
    int total = td.R * td.C;
    for (int i = i0; i < total; i += stride) {
      int c = i / td.R;
      int r = i - c * td.R;
      td.d[i] = f2bf(td.s[(size_t)(td.r0 + r) * td.ld + c]);
    }
  }
}

// block 0: exclusive scan of deg; blocks 1..79: batch bounds; block 80: bias concat vectors
__global__ void scan_bounds(const int* __restrict__ deg, int* __restrict__ rowstart,
                            int* __restrict__ cursor, const int* __restrict__ batch,
                            int* __restrict__ bstart,
                            const float* __restrict__ g1b1, const float* __restrict__ g2b1,
                            float* __restrict__ b1cat1, float* __restrict__ b1cat2) {
  if (blockIdx.x == 0) {
    __shared__ int part[256];
    int t = threadIdx.x;
    int c0 = t * 80; if (c0 > NN) c0 = NN;
    int c1 = c0 + 80; if (c1 > NN) c1 = NN;
    int s = 0;
    for (int i = c0; i < c1; ++i) s += deg[i];
    part[t] = s;
    __syncthreads();
    if (t == 0) {
      int run = 0;
      for (int i = 0; i < 256; ++i) { int v = part[i]; part[i] = run; run += v; }
    }
    __syncthreads();
    int run = part[t];
    for (int i = c0; i < c1; ++i) { rowstart[i] = run; cursor[i] = run; run += deg[i]; }
    if (t == 255) rowstart[NN] = run;   // == NE
  } else if (blockIdx.x == 80) {
    int t = threadIdx.x;
    b1cat1[t] = g1b1[t]; b1cat1[256 + t] = 0.f;
    b1cat2[t] = g2b1[t]; b1cat2[256 + t] = 0.f;
  } else {
    int n = (blockIdx.x - 1) * 256 + threadIdx.x;
    if (n >= NN) return;
    int bn = batch[n];
    if (n == 0) {
      for (int b2 = 0; b2 <= bn; ++b2) bstart[b2] = 0;
    } else {
      int bp = batch[n - 1];
      for (int b2 = bp + 1; b2 <= bn; ++b2) bstart[b2] = n;
    }
    if (n == NN - 1) {
      for (int b2 = bn + 1; b2 <= NBATCH; ++b2) bstart[b2] = NN;
    }
  }
}

__global__ void fillcsr(const int* __restrict__ srcI, const int* __restrict__ dstI,
                        int* __restrict__ cursor, int* __restrict__ sSrc,
                        int* __restrict__ sDst) {
  int e = blockIdx.x * 256 + threadIdx.x;
  if (e < NE) {
    int d = dstI[e];
    int slot = atomicAdd(&cursor[d], 1);
    sDst[slot] = d;
    sSrc[slot] = srcI[e];
  }
}

// ---------------- generic transposed-weight GEMM: Out[r][f] = In[r][:] . WT[f][:] + bias ----------------
__global__ __launch_bounds__(512, 4) void gemmT(
    const unsigned short* __restrict__ WT, const unsigned short* __restrict__ In,
    const float* __restrict__ bias, unsigned short* __restrict__ Out,
    int M, int K, int Nout, int ldo) {
  const int tid = threadIdx.x;
  const int lane = tid & 63, w = tid >> 6;
  const int wf = w >> 1, we = w & 1;
  const int l15 = lane & 15, q = lane >> 4;
  const int fb = blockIdx.x * 256 + wf * 64;
  const int rb = blockIdx.y * 128 + we * 64;
  f32x4 acc[4][4] = {};
  const short8 zz = {0, 0, 0, 0, 0, 0, 0, 0};
  for (int kc = 0; kc < K; kc += 32) {
    short8 a[4], bq[4];
#pragma unroll
    for (int i = 0; i < 4; ++i) {
      if (fb + i * 16 < Nout)
        a[i] = *(const short8*)(WT + (size_t)(fb + i * 16 + l15) * K + kc + q * 8);
      else
        a[i] = zz;
      int r = rb + i * 16 + l15;
      if (r >= M) r = M - 1;  // clamp: stores guarded below
      bq[i] = *(const short8*)(In + (size_t)r * K + kc + q * 8);
    }
#pragma unroll
    for (int i = 0; i < 4; ++i)
#pragma unroll
      for (int j = 0; j < 4; ++j)
        acc[i][j] = __builtin_amdgcn_mfma_f32_16x16x32_bf16(a[i], bq[j], acc[i][j], 0, 0, 0);
  }
#pragma unroll
  for (int i = 0; i < 4; ++i) {
    int f0 = fb + i * 16 + q * 4;
    if (f0 >= Nout) continue;
    float4 bs = make_float4(0.f, 0.f, 0.f, 0.f);
    if (bias) bs = *(const float4*)(bias + f0);
#pragma unroll
    for (int j = 0; j < 4; ++j) {
      int r = rb + j * 16 + l15;
      if (r >= M) continue;
      ushort4 o;
      o.x = f2bf(acc[i][j][0] + bs.x);
      o.y = f2bf(acc[i][j][1] + bs.y);
      o.z = f2bf(acc[i][j][2] + bs.z);
      o.w = f2bf(acc[i][j][3] + bs.w);
      *(ushort4*)(Out + (size_t)r * ldo + f0) = o;
    }
  }
}

// ---------------- fused per-edge MLP + dst-segmented aggregation (verified r11 kernel) ----------------
// h1 = relu(PQ[sDst][0:256] + PQ[sSrc][256:512])  (b1 pre-folded into PQ dst half via gemm bias)
// h2 = relu(h1 @ W2 + b2); m = h2 @ W3 (bf16 LDS); segmented dst-run sum -> agg (+len*b3)
__global__ __launch_bounds__(512, 4) void edge_mlp_f(
    const unsigned short* __restrict__ PQ, const int* __restrict__ sSrc,
    const int* __restrict__ sDst,
    const unsigned short* __restrict__ W2T, const float* __restrict__ b2,
    const unsigned short* __restrict__ W3T, const float* __restrict__ b3,
    int* __restrict__ segcnt, int* __restrict__ segbuf, float* __restrict__ agg) {
  __shared__ __align__(16) unsigned short h[128 * 256];  // 64 KB -> 2 blocks/CU
  const int tid = threadIdx.x;
  const int e0 = blockIdx.x * 128;

  {  // phase 0: gather + h1
    int r = tid & 127;
    int c0 = (tid >> 7) * 64;
    int dn = sDst[e0 + r];
    int sn = sSrc[e0 + r];
    const unsigned short* pd = PQ + (size_t)dn * 512 + c0;
    const unsigned short* ps = PQ + (size_t)sn * 512 + 256 + c0;
#pragma unroll
    for (int i = 0; i < 8; ++i) {
      short8 dv = *(const short8*)(pd + i * 8);
      short8 sv = *(const short8*)(ps + i * 8);
      short8 o;
#pragma unroll
      for (int j = 0; j < 8; ++j) {
        float v = bf2fs(dv[j]) + bf2fs(sv[j]);
        o[j] = (short)f2bf(fmaxf(v, 0.f));
      }
      *(short8*)&h[HOFF(r, c0 + i * 8)] = o;
    }
  }
  __syncthreads();

  const int lane = tid & 63, w = tid >> 6;
  const int wf = w >> 1, we = w & 1;
  const int l15 = lane & 15, q = lane >> 4;
  const int fb = wf * 64, eb = we * 64;
  f32x4 acc[4][4];

  // ---- GEMM1: h2^T = W2T @ h1^T ----
#pragma unroll
  for (int i = 0; i < 4; ++i)
#pragma unroll
    for (int j = 0; j < 4; ++j) { f32x4 z = {0.f, 0.f, 0.f, 0.f}; acc[i][j] = z; }
  for (int kc = 0; kc < 256; kc += 32) {
    short8 a[4], bq[4];
#pragma unroll
    for (int i = 0; i < 4; ++i)
      a[i] = *(const short8*)(W2T + (size_t)(fb + i * 16 + l15) * 256 + kc + q * 8);
#pragma unroll
    for (int j = 0; j < 4; ++j)
      bq[j] = *(const short8*)&h[HOFF(eb + j * 16 + l15, kc + q * 8)];
#pragma unroll
    for (int i = 0; i < 4; ++i)
#pragma unroll
      for (int j = 0; j < 4; ++j)
        acc[i][j] = __builtin_amdgcn_mfma_f32_16x16x32_bf16(a[i], bq[j], acc[i][j], 0, 0, 0);
  }
  __syncthreads();  // all reads of h1 done
#pragma unroll
  for (int i = 0; i < 4; ++i) {
    int f0 = fb + i * 16 + q * 4;
    float4 bs = *(const float4*)(b2 + f0);
#pragma unroll
    for (int j = 0; j < 4; ++j) {
      int e = eb + j * 16 + l15;
      ushort4 o;
      o.x = f2bf(fmaxf(acc[i][j][0] + bs.x, 0.f));
      o.y = f2bf(fmaxf(acc[i][j][1] + bs.y, 0.f));
      o.z = f2bf(fmaxf(acc[i][j][2] + bs.z, 0.f));
      o.w = f2bf(fmaxf(acc[i][j][3] + bs.w, 0.f));
      *(ushort4*)&h[HOFF(e, f0)] = o;  // h2
    }
  }
  __syncthreads();

  // ---- GEMM2: m^T = W3T @ h2^T ----
#pragma unroll
  for (int i = 0; i < 4; ++i)
#pragma unroll
    for (int j = 0; j < 4; ++j) { f32x4 z = {0.f, 0.f, 0.f, 0.f}; acc[i][j] = z; }
  for (int kc = 0; kc < 256; kc += 32) {
    short8 a[4], bq[4];
#pragma unroll
    for (int i = 0; i < 4; ++i)
      a[i] = *(const short8*)(W3T + (size_t)(fb + i * 16 + l15) * 256 + kc + q * 8);
#pragma unroll
    for (int j = 0; j < 4; ++j)
      bq[j] = *(const short8*)&h[HOFF(eb + j * 16 + l15, kc + q * 8)];
#pragma unroll
    for (int i = 0; i < 4; ++i)
#pragma unroll
      for (int j = 0; j < 4; ++j)
        acc[i][j] = __builtin_amdgcn_mfma_f32_16x16x32_bf16(a[i], bq[j], acc[i][j], 0, 0, 0);
  }
  __syncthreads();  // all reads of h2 done before overwrite
#pragma unroll
  for (int i = 0; i < 4; ++i) {
    int f0 = fb + i * 16 + q * 4;
#pragma unroll
    for (int j = 0; j < 4; ++j) {
      int e = eb + j * 16 + l15;
      ushort4 o;
      o.x = f2bf(acc[i][j][0]); o.y = f2bf(acc[i][j][1]);
      o.z = f2bf(acc[i][j][2]); o.w = f2bf(acc[i][j][3]);
      *(ushort4*)&h[HOFF(e, f0)] = o;  // m
    }
  }
  if (tid < 128) {
    int d0 = sDst[e0 + tid];
    bool flag = (tid == 0) || (sDst[e0 + tid - 1] != d0);
    if (flag) {
      int idx = atomicAdd(&segcnt[blockIdx.x], 1);
      segbuf[blockIdx.x * 128 + idx] = tid;
    }
  }
  __syncthreads();

  // segmented reduction: 8 groups x 64 lanes (4 feats/lane), fp32
  {
    int cnt = segcnt[blockIdx.x];
    int f4 = (tid & 63) * 4;
    int sg = tid >> 6;
    const int* sb = segbuf + blockIdx.x * 128;
    float4 b3v = *(const float4*)(b3 + f4);
    for (int k = sg; k < cnt; k += 8) {
      int start = sb[k];
      int end = 128;
      for (int j2 = 0; j2 < cnt; ++j2) {
        int v = sb[j2];
        if (v > start && v < end) end = v;
      }
      int node = sDst[e0 + start];
      float s0 = 0.f, s1 = 0.f, s2 = 0.f, s3 = 0.f;
      for (int rr = start; rr < end; ++rr) {
        ushort4 v = *(const ushort4*)&h[HOFF(rr, f4)];
        s0 += bf2f(v.x); s1 += bf2f(v.y); s2 += bf2f(v.z); s3 += bf2f(v.w);
      }
      float c = (float)(end - start);
      s0 += c * b3v.x; s1 += c * b3v.y; s2 += c * b3v.z; s3 += c * b3v.w;
      float* pr = agg + (size_t)node * 256 + f4;
      if (start == 0 || end == 128) {  // run may continue in neighbor tile
        atomicAdd(pr + 0, s0); atomicAdd(pr + 1, s1);
        atomicAdd(pr + 2, s2); atomicAdd(pr + 3, s3);
      } else {                         // wholly inside this tile: unique owner
        *(float4*)pr = make_float4(s0, s1, s2, s3);
      }
    }
  }
}

// ---------------- relu + layernorm, fp32 in -> bf16 out ----------------
__global__ void relu_ln(const float* __restrict__ agg, const float* __restrict__ g,
                        const float* __restrict__ b, unsigned short* __restrict__ out) {
  int row = blockIdx.x * 4 + (threadIdx.x >> 6);
  int lane = threadIdx.x & 63;
  if (row >= NN) return;
  float4 v = *(const float4*)(agg + (size_t)row * 256 + lane * 4);
  v.x = fmaxf(v.x, 0.f); v.y = fmaxf(v.y, 0.f); v.z = fmaxf(v.z, 0.f); v.w = fmaxf(v.w, 0.f);
  float s = v.x + v.y + v.z + v.w;
  float sq = v.x * v.x + v.y * v.y + v.z * v.z + v.w * v.w;
  for (int off = 32; off >= 1; off >>= 1) {
    s += __shfl_xor(s, off);
    sq += __shfl_xor(sq, off);
  }
  float mu = s * (1.f / 256.f);
  float var = sq * (1.f / 256.f) - mu * mu;
  float rs = rsqrtf(var + 1e-5f);
  float4 gg = *(const float4*)(g + lane * 4);
  float4 bb = *(const float4*)(b + lane * 4);
  ushort4 o;
  o.x = f2bf((v.x - mu) * rs * gg.x + bb.x);
  o.y = f2bf((v.y - mu) * rs * gg.y + bb.y);
  o.z = f2bf((v.z - mu) * rs * gg.z + bb.z);
  o.w = f2bf((v.w - mu) * rs * gg.w + bb.w);
  *(ushort4*)(out + (size_t)row * 256 + lane * 4) = o;
}

// ---------------- fused assignment MLP + gumbel softmax (64 node-rows per block) ----------------
__global__ __launch_bounds__(512, 4) void assign_gumbel(
    const unsigned short* __restrict__ x2b, const unsigned short* __restrict__ aw1T,
    const float* __restrict__ ab1, const unsigned short* __restrict__ aw2T,
    const float* __restrict__ ab2, const float* __restrict__ u,
    float* __restrict__ sf, float* __restrict__ entacc, float* __restrict__ avgacc) {
  __shared__ __align__(16) unsigned short sh[64 * 256];   // 32 KB
  __shared__ float sh_logit[64 * 33];
  __shared__ float lavg[32];
  __shared__ float lent;
  const int tid = threadIdx.x;
  const int n0 = blockIdx.x * 64;
  if (tid < 32) lavg[tid] = 0.f;
  if (tid == 0) lent = 0.f;

  const int lane = tid & 63, w = tid >> 6;
  const int l15 = lane & 15, q = lane >> 4;

  {  // phase A: assh tile
    const int wf = w >> 1, we = w & 1;
    const int fb = wf * 64, eb = we * 32;
    f32x4 acc[4][2];
#pragma unroll
    for (int i = 0; i < 4; ++i)
#pragma unroll
      for (int j = 0; j < 2; ++j) { f32x4 z = {0.f, 0.f, 0.f, 0.f}; acc[i][j] = z; }
    for (int kc = 0; kc < 256; kc += 32) {
      short8 a[4], bq[2];
#pragma unroll
      for (int i = 0; i < 4; ++i)
        a[i] = *(const short8*)(aw1T + (size_t)(fb + i * 16 + l15) * 256 + kc + q * 8);
#pragma unroll
      for (int j = 0; j < 2; ++j) {
        int rr = n0 + eb + j * 16 + l15;
        if (rr >= NN) rr = NN - 1;
        bq[j] = *(const short8*)(x2b + (size_t)rr * 256 + kc + q * 8);
      }
#pragma unroll
      for (int i = 0; i < 4; ++i)
#pragma unroll
        for (int j = 0; j < 2; ++j)
          acc[i][j] = __builtin_amdgcn_mfma_f32_16x16x32_bf16(a[i], bq[j], acc[i][j], 0, 0, 0);
    }
#pragma unroll
    for (int i = 0; i < 4; ++i) {
      int f0 = fb + i * 16 + q * 4;
      float4 bs = *(const float4*)(ab1 + f0);
#pragma unroll
      for (int j = 0; j < 2; ++j) {
        int e = eb + j * 16 + l15;
        ushort4 o;
        o.x = f2bf(fmaxf(acc[i][j][0] + bs.x, 0.f));
        o.y = f2bf(fmaxf(acc[i][j][1] + bs.y, 0.f));
        o.z = f2bf(fmaxf(acc[i][j][2] + bs.z, 0.f));
        o.w = f2bf(fmaxf(acc[i][j][3] + bs.w, 0.f));
        *(ushort4*)&sh[HOFF(e, f0)] = o;
      }
    }
  }
  __syncthreads();

  {  // phase B: logits (N=32). wave w: row-group rg=w&3, feat-group fg=w>>2 (fg<2)
    const int rg = w & 3, fg = w >> 2;
    if (fg < 2) {
      f32x4 acc = {0.f, 0.f, 0.f, 0.f};
      for (int kc = 0; kc < 256; kc += 32) {
        short8 a = *(const short8*)(aw2T + (size_t)(fg * 16 + l15) * 256 + kc + q * 8);
        short8 bq = *(const short8*)&sh[HOFF(rg * 16 + l15, kc + q * 8)];
        acc = __builtin_amdgcn_mfma_f32_16x16x32_bf16(a, bq, acc, 0, 0, 0);
      }
      int rowL = rg * 16 + l15;
#pragma unroll
      for (int t2 = 0; t2 < 4; ++t2) {
        int f = fg * 16 + q * 4 + t2;
        sh_logit[rowL * 33 + f] = acc[t2] + ab2[f];
      }
    }
  }
  __syncthreads();

  // phase C: gumbel softmax, 4 threads per row (8 slots each)
  if (tid < 256) {
    int rowL = tid >> 2, sub = tid & 3;
    int n = n0 + rowL;
    if (n < NN) {
      int j0 = sub * 8;
      float z[8];
      float4 u0 = *(const float4*)(u + (size_t)n * 32 + j0);
      float4 u1 = *(const float4*)(u + (size_t)n * 32 + j0 + 4);
      float uu[8] = {u0.x, u0.y, u0.z, u0.w, u1.x, u1.y, u1.z, u1.w};
      float m = -1e30f;
#pragma unroll
      for (int j = 0; j < 8; ++j) {
        z[j] = sh_logit[rowL * 33 + j0 + j] - logf(-logf(uu[j] + 1e-9f) + 1e-9f);
        m = fmaxf(m, z[j]);
      }
      m = fmaxf(m, __shfl_xor(m, 1));
      m = fmaxf(m, __shfl_xor(m, 2));
      float sum = 0.f;
#pragma unroll
      for (int j = 0; j < 8; ++j) { z[j] = expf(z[j] - m); sum += z[j]; }
      sum += __shfl_xor(sum, 1);
      sum += __shfl_xor(sum, 2);
      float inv = 1.f / sum;
      float ent = 0.f;
      float so[8];
#pragma unroll
      for (int j = 0; j < 8; ++j) {
        float sj = z[j] * inv;
        so[j] = sj;
        ent += sj * logf(sj + 1e-9f);
        atomicAdd(&lavg[j0 + j], sj);
      }
      *(float4*)(sf + (size_t)n * 32 + j0) = make_float4(so[0], so[1], so[2], so[3]);
      *(float4*)(sf + (size_t)n * 32 + j0 + 4) = make_float4(so[4], so[5], so[6], so[7]);
      ent += __shfl_xor(ent, 1);
      ent += __shfl_xor(ent, 2);
      if (sub == 0) atomicAdd(&lent, ent);
    }
  }
  __syncthreads();
  if (tid < 32) atomicAdd(&avgacc[tid], lavg[tid]);
  if (tid == 0) atomicAdd(entacc, lent);
}

// ---------------- pooled[b,s,h] = sum_n x2[n,h]*s[n,s] ----------------
__global__ void pool_kernel(const unsigned short* __restrict__ x2b, const float* __restrict__ sf,
                            const int* __restrict__ bstart, float* __restrict__ pooled) {
  int b = blockIdx.x, ci = blockIdx.y;
  int n0b = bstart[b], n1b = bstart[b + 1];
  int t = threadIdx.x;
  int si = t >> 3;          // 0..31
  int hb = (t & 7) * 32;    // 0..224
  float acc[32];
#pragma unroll
  for (int k = 0; k < 32; ++k) acc[k] = 0.f;
  for (int nst = n0b + ci * 128; nst < n1b; nst += gridDim.y * 128) {
    int nend = (nst + 128 < n1b) ? nst + 128 : n1b;
    for (int n = nst; n < nend; ++n) {
      float sv = sf[(size_t)n * 32 + si];
      const unsigned short* xr = x2b + (size_t)n * 256 + hb;
#pragma unroll
      for (int k2 = 0; k2 < 4; ++k2) {
        short8 xv = *(const short8*)(xr + k2 * 8);
#pragma unroll
        for (int jj = 0; jj < 8; ++jj) acc[k2 * 8 + jj] = fmaf(sv, bf2fs(xv[jj]), acc[k2 * 8 + jj]);
      }
    }
  }
  float* pp = pooled + (size_t)(b * 32 + si) * 256 + hb;
#pragma unroll
  for (int k = 0; k < 32; ++k) atomicAdd(pp + k, acc[k]);
}

// ---------------- fused output MLP (+ loss in block 0): latent = relu(pooled@ow1+ob1)@ow2+ob2 ----
__global__ __launch_bounds__(512, 4) void out_mlp(
    const float* __restrict__ pooled, const unsigned short* __restrict__ ow1T,
    const float* __restrict__ ob1, const unsigned short* __restrict__ ow2T,
    const float* __restrict__ ob2, float* __restrict__ latent,
    const float* __restrict__ accs, float* __restrict__ outloss) {
  __shared__ __align__(16) unsigned short sh[64 * 256];   // hid tile, 32 KB
  const int tid = threadIdx.x;
  const int n0 = blockIdx.x * 64;
  const int lane = tid & 63, w = tid >> 6;
  const int l15 = lane & 15, q = lane >> 4;

  if (blockIdx.x == 0 && tid < 64) {  // loss (accs ready: assign_gumbel completed earlier)
    float d = 0.f;
    if (tid < 32) {
      float a = accs[16 + tid] * (1.f / NN);
      d = a * logf(a + 1e-9f);
    }
    for (int off = 32; off >= 1; off >>= 1) d += __shfl_xor(d, off);
    if (tid == 0) outloss[0] = -accs[0] * (1.f / NN) + d;
  }

  {  // phase A: hid = relu(pooled @ ow1 + ob1), pooled converted inline to bf16
    const int wf = w >> 1, we = w & 1;
    const int fb = wf * 64, eb = we * 32;
    f32x4 acc[4][2];
#pragma unroll
    for (int i = 0; i < 4; ++i)
#pragma unroll
      for (int j = 0; j < 2; ++j) { f32x4 z = {0.f, 0.f, 0.f, 0.f}; acc[i][j] = z; }
    for (int kc = 0; kc < 256; kc += 32) {
      short8 a[4], bq[2];
#pragma unroll
      for (int i = 0; i < 4; ++i)
        a[i] = *(const short8*)(ow1T + (size_t)(fb + i * 16 + l15) * 256 + kc + q * 8);
#pragma unroll
      for (int j = 0; j < 2; ++j) {
        int rr = n0 + eb + j * 16 + l15;
        const float* pr = pooled + (size_t)rr * 256 + kc + q * 8;
        float4 lo = *(const float4*)pr;
        float4 hi = *(const float4*)(pr + 4);
        short8 o;
        o[0] = (short)f2bf(lo.x); o[1] = (short)f2bf(lo.y);
        o[2] = (short)f2bf(lo.z); o[3] = (short)f2bf(lo.w);
        o[4] = (short)f2bf(hi.x); o[5] = (short)f2bf(hi.y);
        o[6] = (short)f2bf(hi.z); o[7] = (short)f2bf(hi.w);
        bq[j] = o;
      }
#pragma unroll
      for (int i = 0; i < 4; ++i)
#pragma unroll
        for (int j = 0; j < 2; ++j)
          acc[i][j] = __builtin_amdgcn_mfma_f32_16x16x32_bf16(a[i], bq[j], acc[i][j], 0, 0, 0);
    }
#pragma unroll
    for (int i = 0; i < 4; ++i) {
      int f0 = fb + i * 16 + q * 4;
      float4 bs = *(const float4*)(ob1 + f0);
#pragma unroll
      for (int j = 0; j < 2; ++j) {
        int e = eb + j * 16 + l15;
        ushort4 o;
        o.x = f2bf(fmaxf(acc[i][j][0] + bs.x, 0.f));
        o.y = f2bf(fmaxf(acc[i][j][1] + bs.y, 0.f));
        o.z = f2bf(fmaxf(acc[i][j][2] + bs.z, 0.f));
        o.w = f2bf(fmaxf(acc[i][j][3] + bs.w, 0.f));
        *(ushort4*)&sh[HOFF(e, f0)] = o;
      }
    }
  }
  __syncthreads();

  {  // phase B: latent = hid @ ow2 + ob2 (Nout=128)
    const int wf = w >> 1, we = w & 1;
    const int fb = wf * 32, eb = we * 32;
    f32x4 acc[2][2];
#pragma unroll
    for (int i = 0; i < 2; ++i)
#pragma unroll
      for (int j = 0; j < 2; ++j) { f32x4 z = {0.f, 0.f, 0.f, 0.f}; acc[i][j] = z; }
    for (int kc = 0; kc < 256; kc += 32) {
      short8 a[2], bq[2];
#pragma unroll
      for (int i = 0; i < 2; ++i)
        a[i] = *(const short8*)(ow2T + (size_t)(fb + i * 16 + l15) * 256 + kc + q * 8);
#pragma unroll
      for (int j = 0; j < 2; ++j)
        bq[j] = *(const short8*)&sh[HOFF(eb + j * 16 + l15, kc + q * 8)];
#pragma unroll
      for (int i = 0; i < 2; ++i)
#pragma unroll
        for (int j = 0; j < 2; ++j)
          acc[i][j] = __builtin_amdgcn_mfma_f32_16x16x32_bf16(a[i], bq[j], acc[i][j], 0, 0, 0);
    }
#pragma unroll
    for (int i = 0; i < 2; ++i) {
      int f0 = fb + i * 16 + q * 4;
      float4 bs = *(const float4*)(ob2 + f0);
#pragma unroll
      for (int j = 0; j < 2; ++j) {
        int rr = n0 + eb + j * 16 + l15;
        *(float4*)(latent + (size_t)rr * 128 + f0) =
            make_float4(acc[i][j][0] + bs.x, acc[i][j][1] + bs.y,
                        acc[i][j][2] + bs.z, acc[i][j][3] + bs.w);
      }
    }
  }
}

// ---------------- orchestration ----------------
extern "C" void kernel_launch(void* const* d_in, const int* in_sizes, int n_in,
                              void* d_out, int out_size, void* d_ws, size_t ws_size,
                              hipStream_t stream) {
  (void)in_sizes; (void)n_in; (void)out_size; (void)ws_size;
  const float* x = (const float*)d_in[0];
  const float* u = (const float*)d_in[1];
  const int* ei = (const int*)d_in[2];
  const int* batch = (const int*)d_in[3];
  const float* g1w1 = (const float*)d_in[4];
  const float* g1b1 = (const float*)d_in[5];
  const float* g1w2 = (const float*)d_in[6];
  const float* g1b2 = (const float*)d_in[7];
  const float* g1w3 = (const float*)d_in[8];
  const float* g1b3 = (const float*)d_in[9];
  const float* ln1g = (const float*)d_in[10];
  const float* ln1b = (const float*)d_in[11];
  const float* g2w1 = (const float*)d_in[12];
  const float* g2b1 = (const float*)d_in[13];
  const float* g2w2 = (const float*)d_in[14];
  const float* g2b2 = (const float*)d_in[15];
  const float* g2w3 = (const float*)d_in[16];
  const float* g2b3 = (const float*)d_in[17];
  const float* ln2g = (const float*)d_in[18];
  const float* ln2b = (const float*)d_in[19];
  const float* aw1 = (const float*)d_in[20];
  const float* ab1 = (const float*)d_in[21];
  const float* aw2 = (const float*)d_in[22];
  const float* ab2 = (const float*)d_in[23];
  const float* ow1 = (const float*)d_in[24];
  const float* ob1 = (const float*)d_in[25];
  const float* ow2 = (const float*)d_in[26];
  const float* ob2 = (const float*)d_in[27];
  const int* srcI = ei;        // edge_index[0] = src
  const int* dstI = ei + NE;   // edge_index[1] = dst

  char* wp = (char*)d_ws;
  size_t off = 0;
  auto alloc = [&](size_t bytes) {
    void* p = wp + off;
    off += (bytes + 255) & ~(size_t)255;
    return p;
  };
  unsigned short* W1catT = (unsigned short*)alloc((size_t)512 * 64 * 2);
  unsigned short* W2catT = (unsigned short*)alloc((size_t)512 * 256 * 2);
  unsigned short* g1w2T = (unsigned short*)alloc((size_t)256 * 256 * 2);
  unsigned short* g1w3T = (unsigned short*)alloc((size_t)256 * 256 * 2);
  unsigned short* g2w2T = (unsigned short*)alloc((size_t)256 * 256 * 2);
  unsigned short* g2w3T = (unsigned short*)alloc((size_t)256 * 256 * 2);
  unsigned short* aw1T = (unsigned short*)alloc((size_t)256 * 256 * 2);
  unsigned short* aw2T = (unsigned short*)alloc((size_t)32 * 256 * 2);
  unsigned short* ow1T = (unsigned short*)alloc((size_t)256 * 256 * 2);
  unsigned short* ow2T = (unsigned short*)alloc((size_t)128 * 256 * 2);
  unsigned short* xb = (unsigned short*)alloc((size_t)NN * 64 * 2);
  unsigned short* PQ = (unsigned short*)alloc((size_t)NN * 512 * 2);
  unsigned short* x1b = (unsigned short*)alloc((size_t)NN * 256 * 2);
  unsigned short* x2b = (unsigned short*)alloc((size_t)NN * 256 * 2);
  int* bstart = (int*)alloc(32 * 4);
  int* cursor = (int*)alloc((size_t)NN * 4);
  int* rowstart = (int*)alloc((size_t)(NN + 1) * 4);
  int* sSrc = (int*)alloc((size_t)NE * 4);
  int* sDst = (int*)alloc((size_t)NE * 4);
  int* segbuf = (int*)alloc((size_t)2 * NTILE * 128 * 4);
  float* b1cat1 = (float*)alloc(512 * 4);
  float* b1cat2 = (float*)alloc(512 * 4);
  // ---- contiguous zero-init region (single memset) ----
  char* zbase = (char*)(wp + off);
  float* accs = (float*)alloc(64 * 4);
  float* pooled = (float*)alloc((size_t)512 * 256 * 4);
  int* deg = (int*)alloc((size_t)NN * 4);
  int* segcnt = (int*)alloc((size_t)2 * NTILE * 4);
  float* agg1 = (float*)alloc((size_t)NN * 256 * 4);
  float* agg2 = (float*)alloc((size_t)NN * 256 * 4);
  size_t zbytes = (size_t)((char*)(wp + off) - zbase);

  float* out_f = (float*)d_out;
  float* out_latent = out_f;                 // [16*32*128] = 65536
  float* out_s = out_f + 65536;              // [20000*32]
  float* out_loss = out_f + 65536 + 640000;  // [1]

  TDs tds;
  tds.t[0] = {g1w1, W1catT, 64, 256, 0, 256};
  tds.t[1] = {g1w1, W1catT + 256 * 64, 64, 256, 64, 256};
  tds.t[2] = {g1w2, g1w2T, 256, 256, 0, 256};
  tds.t[3] = {g1w3, g1w3T, 256, 256, 0, 256};
  tds.t[4] = {g2w1, W2catT, 256, 256, 0, 256};
  tds.t[5] = {g2w1, W2catT + 256 * 256, 256, 256, 256, 256};
  tds.t[6] = {g2w2, g2w2T, 256, 256, 0, 256};
  tds.t[7] = {g2w3, g2w3T, 256, 256, 0, 256};
  tds.t[8] = {aw1, aw1T, 256, 256, 0, 256};
  tds.t[9] = {aw2, aw2T, 256, 32, 0, 32};
  tds.t[10] = {ow1, ow1T, 256, 256, 0, 256};
  tds.t[11] = {ow2, ow2T, 256, 128, 0, 128};
  tds.t[12] = {x, xb, NN * 64, 1, 0, 0};

  (void)hipMemsetAsync(zbase, 0, zbytes, stream);   // accs+pooled+deg+segcnt+agg1+agg2
  // weight prep + degree histogram in one dispatch (y==13 -> hist)
  wprep<<<dim3(128, 14), 256, 0, stream>>>(tds, dstI, deg);

  // CSR scan + batch bounds + bias concat, then permutation fill
  scan_bounds<<<dim3(81), 256, 0, stream>>>(deg, rowstart, cursor, batch, bstart,
                                            g1b1, g2b1, b1cat1, b1cat2);
  fillcsr<<<dim3(1250), 256, 0, stream>>>(srcI, dstI, cursor, sSrc, sDst);

  // layer 1 (b1 folded into PQ dst half)
  gemmT<<<dim3(2, 157), 512, 0, stream>>>(W1catT, xb, b1cat1, PQ, NN, 64, 512, 512);
  edge_mlp_f<<<dim3(NTILE), 512, 0, stream>>>(PQ, sSrc, sDst, g1w2T, g1b2, g1w3T, g1b3,
                                              segcnt, segbuf, agg1);
  relu_ln<<<dim3(5000), 256, 0, stream>>>(agg1, ln1g, ln1b, x1b);

  // layer 2
  gemmT<<<dim3(2, 157), 512, 0, stream>>>(W2catT, x1b, b1cat2, PQ, NN, 256, 512, 512);
  edge_mlp_f<<<dim3(NTILE), 512, 0, stream>>>(PQ, sSrc, sDst, g2w2T, g2b2, g2w3T, g2b3,
                                              segcnt + NTILE, segbuf + (size_t)NTILE * 128, agg2);
  relu_ln<<<dim3(5000), 256, 0, stream>>>(agg2, ln2g, ln2b, x2b);

  // fused assignment MLP + gumbel softmax (s fp32 to d_out)
  assign_gumbel<<<dim3(313), 512, 0, stream>>>(x2b, aw1T, ab1, aw2T, ab2, u,
                                               out_s, accs, accs + 16);

  // pooling + fused output MLP (+loss)
  pool_kernel<<<dim3(16, 12), 256, 0, stream>>>(x2b, out_s, bstart, pooled);
  out_mlp<<<dim3(8), 512, 0, stream>>>(pooled, ow1T, ob1, ow2T, ob2, out_latent,
                                       accs, out_loss);
}